// Round 17
// baseline (284.712 us; speedup 1.0000x reference)
//
#include <hip/hip_runtime.h>
#include <hip/hip_bf16.h>

typedef unsigned short u16;
typedef __attribute__((ext_vector_type(8))) short short8;
typedef __attribute__((ext_vector_type(4))) float f32x4;

__device__ __forceinline__ u16 f2bf(float f) {
  __hip_bfloat16 h = __float2bfloat16(f);   // HW RNE; compiler packs to v_cvt_pk_bf16_f32
  return *reinterpret_cast<u16*>(&h);
}

// ---------------- merged weight transpose+cvt: dst[c][r] = (bf16)W[r][c] ----------
// tight 1-D tile grid: seg0 Wq (64x64 tiles), seg1 Wk (16x64), seg2 Wv (16x64),
// seg3 Wo (64x64) -> 10240 blocks total, no early-return waste.
struct TP4 {
  const float *s0, *s1, *s2, *s3;
  u16 *d0, *d1, *d2, *d3;
};
__global__ __launch_bounds__(256)
void transpose4_kernel(TP4 tp) {
  int bid = blockIdx.x;
  const float* sf; u16* dst; int C, tx_tiles;
  if (bid < 4096)       { sf = tp.s0; dst = tp.d0; C = 2048; tx_tiles = 64; }
  else if (bid < 5120)  { sf = tp.s1; dst = tp.d1; C = 512;  tx_tiles = 16; bid -= 4096; }
  else if (bid < 6144)  { sf = tp.s2; dst = tp.d2; C = 512;  tx_tiles = 16; bid -= 5120; }
  else                  { sf = tp.s3; dst = tp.d3; C = 2048; tx_tiles = 64; bid -= 6144; }
  const int c0 = (bid % tx_tiles) * 32, r0 = (bid / tx_tiles) * 32;
  const int R = 2048;
  __shared__ u16 tile[32][33];
  const int tx = threadIdx.x, ty = threadIdx.y;
#pragma unroll
  for (int i = 0; i < 4; ++i) {
    int r = r0 + ty + i * 8;
    tile[ty + i * 8][tx] = f2bf(sf[(long)r * C + c0 + tx]);
  }
  __syncthreads();
#pragma unroll
  for (int i = 0; i < 4; ++i) {
    int rr = ty + i * 8;
    dst[(long)(c0 + rr) * R + r0 + tx] = tile[tx][rr];
  }
}

// ---------------- GEMM (up to 3 independent problems per dispatch) ----------------
// C[m][n] = scale * sum_k A[m][k] * Bt[n][k] + bias[n]
// mode: 0 = f32 nt-store, 1 = bf16 store, 2 = bf16 transposed-batched VT[b][n][s]
// BK=32 double-buffered: LDS 32 KB/block -> 4 blocks/CU.
#define BM 128
#define BN 128
#define BK 32

struct GemmP {
  const void* A;
  const u16* B;
  const float* bias;
  void* C;
  int N, K, lda, ldb, ldc, mode;
  float scale;
};
struct Gemm3 {
  GemmP q[3];
  int nb0, nb1;   // block counts of problems 0 and 1
  int nwg;        // total blocks (divisible by 8)
};

template<bool AF32>
__global__ __launch_bounds__(256, 4)
void gemm3_kernel(Gemm3 g) {
  __shared__ __align__(16) u16 lds[2][2][BM * BK];   // 32 KB total
  const int t = threadIdx.x;
  const int w = t >> 6, l = t & 63;

  // bijective XCD swizzle (nwg % 8 == 0)
  const int cpx = g.nwg >> 3;
  const int swz = (blockIdx.x & 7) * cpx + (blockIdx.x >> 3);
  int pi, local;
  if (swz < g.nb0)            { pi = 0; local = swz; }
  else if (swz < g.nb0 + g.nb1) { pi = 1; local = swz - g.nb0; }
  else                        { pi = 2; local = swz - g.nb0 - g.nb1; }
  const GemmP p = g.q[pi];

  const int nTn = p.N / BN;
  const int tm = (local / nTn) * BM;
  const int tn = (local % nTn) * BN;

  const u16*   Ab = (const u16*)p.A + (long)tm * p.lda;
  const float* Af = (const float*)p.A + (long)tm * p.lda;
  const u16*   Bt = p.B + (long)tn * p.ldb;

  const int wr = w >> 1, wc = w & 1;
  f32x4 acc[4][4] = {};
  float aR[16];

  // rows are 32 u16 = 4 slots of 8; XOR swizzle slot ^= row&3 (both sides).
  auto stageB = [&](int kt, int buf) {
#pragma unroll
    for (int i = 0; i < 2; ++i) {
      int c = i * 256 + t;
      int row = c >> 2;
      int slot = (c & 3) ^ (row & 3);
      const u16* gp = Bt + kt * BK + (long)row * p.ldb + slot * 8;
      u16* lp = &lds[buf][1][(i * 256 + w * 64) * 8];
      __builtin_amdgcn_global_load_lds(
          (const __attribute__((address_space(1))) unsigned int*)gp,
          (__attribute__((address_space(3))) unsigned int*)lp, 16, 0, 0);
    }
  };
  auto stageA_bf16 = [&](int kt, int buf) {
#pragma unroll
    for (int i = 0; i < 2; ++i) {
      int c = i * 256 + t;
      int row = c >> 2;
      int slot = (c & 3) ^ (row & 3);
      const u16* gp = Ab + kt * BK + (long)row * p.lda + slot * 8;
      u16* lp = &lds[buf][0][(i * 256 + w * 64) * 8];
      __builtin_amdgcn_global_load_lds(
          (const __attribute__((address_space(1))) unsigned int*)gp,
          (__attribute__((address_space(3))) unsigned int*)lp, 16, 0, 0);
    }
  };
  auto loadA_f32 = [&](int kt) {
    const float* g0 = Af + kt * BK;
#pragma unroll
    for (int i = 0; i < 2; ++i) {
      int c = i * 256 + t;
      int row = c >> 2, slot = c & 3;
      const float4* gp = (const float4*)(g0 + (long)row * p.lda + slot * 8);
      float4 v0 = gp[0], v1 = gp[1];
      aR[i * 8 + 0] = v0.x; aR[i * 8 + 1] = v0.y; aR[i * 8 + 2] = v0.z; aR[i * 8 + 3] = v0.w;
      aR[i * 8 + 4] = v1.x; aR[i * 8 + 5] = v1.y; aR[i * 8 + 6] = v1.z; aR[i * 8 + 7] = v1.w;
    }
  };
  auto writeA = [&](int buf) {
#pragma unroll
    for (int i = 0; i < 2; ++i) {
      int c = i * 256 + t;
      int row = c >> 2, slot = c & 3;
      short8 o;
#pragma unroll
      for (int j = 0; j < 8; ++j) o[j] = (short)f2bf(aR[i * 8 + j]);
      *(short8*)&lds[buf][0][row * 32 + ((slot ^ (row & 3)) * 8)] = o;
    }
  };
  auto compute = [&](int buf) {
    const u16* At  = lds[buf][0];
    const u16* Btl = lds[buf][1];
    short8 af[4], bfr[4];
#pragma unroll
    for (int mi = 0; mi < 4; ++mi) {
      int row = wr * 64 + mi * 16 + (l & 15);
      int slot = (l >> 4) ^ (row & 3);
      af[mi] = *(const short8*)&At[row * 32 + slot * 8];
    }
#pragma unroll
    for (int ni = 0; ni < 4; ++ni) {
      int row = wc * 64 + ni * 16 + (l & 15);
      int slot = (l >> 4) ^ (row & 3);
      bfr[ni] = *(const short8*)&Btl[row * 32 + slot * 8];
    }
#pragma unroll
    for (int mi = 0; mi < 4; ++mi)
#pragma unroll
      for (int ni = 0; ni < 4; ++ni)
        acc[mi][ni] = __builtin_amdgcn_mfma_f32_16x16x32_bf16(
            af[mi], bfr[ni], acc[mi][ni], 0, 0, 0);
  };

  const int nkt = p.K / BK;
  if (AF32) { loadA_f32(0); stageB(0, 0); writeA(0); }
  else      { stageA_bf16(0, 0); stageB(0, 0); }
  __syncthreads();

  int buf = 0;
  for (int kt = 0; kt < nkt; ++kt) {
    if (kt + 1 < nkt) {
      if (AF32) loadA_f32(kt + 1); else stageA_bf16(kt + 1, buf ^ 1);
      stageB(kt + 1, buf ^ 1);
    }
    compute(buf);
    if (AF32 && kt + 1 < nkt) writeA(buf ^ 1);
    __syncthreads();
    buf ^= 1;
  }

  const int cl = l & 15, rj = (l >> 4) * 4;
#pragma unroll
  for (int mi = 0; mi < 4; ++mi) {
#pragma unroll
    for (int ni = 0; ni < 4; ++ni) {
      int cidx = tn + wc * 64 + ni * 16 + cl;
      float bv = p.bias ? p.bias[cidx] : 0.f;
#pragma unroll
      for (int j = 0; j < 4; ++j) {
        int r = tm + wr * 64 + mi * 16 + rj + j;
        float v = acc[mi][ni][j] * p.scale + bv;
        if (p.mode == 2) {
          // VT[b][cidx][s]: b = r>>10, s = r&1023
          ((u16*)p.C)[((long)(r >> 10)) * 524288 + (long)cidx * 1024 + (r & 1023)] = f2bf(v);
        } else {
          long idx = (long)r * p.ldc + cidx;
          if (p.mode == 1) ((u16*)p.C)[idx] = f2bf(v);
          else             __builtin_nontemporal_store(v, &((float*)p.C)[idx]);
        }
      }
    }
  }
}

// ---------------- fused scores -> softmax -> PV (swapped-MFMA, paired phases) -----
// 1-D grid 2048, XCD-swizzled. 512 threads = 8 waves (wq 0..1, wcol 0..3).
// Scores: 8 pair-phases (kv[2][2] ring). PV: 8 pair-phases (same ring) with P
// pairs through p4[2][2]. red[2] separate (1 KB) -> one fewer softmax barrier.
// attn f32 stores after PV, NON-TEMPORAL. Prologue uses counted vmcnt(4)
// (each wave's Q load is its oldest -> retired before its barrier; K0/K1 stay
// in flight; the scores-phase __syncthreads drains them before first use).
__global__ __launch_bounds__(512, 4)
void fused_attn_kernel(const u16* __restrict__ Qg, const u16* __restrict__ Kg,
                       const u16* __restrict__ Vg, float* __restrict__ attnF,
                       u16* __restrict__ AO) {
  __shared__ __align__(16) u16 kv[2][2][64 * 128];  // 64 KB (pair ring)
  __shared__ __align__(16) u16 p4[2][2][32 * 64];   // 16 KB: Q stage / P pair ring
  __shared__ float red[2][4][32];                   // 1 KB, double-buffered

  const int t = threadIdx.x;
  const int w = t >> 6, l = t & 63;
  const int wq = w >> 2, wcol = w & 3;
  const int i_ = blockIdx.x;
  const int swz = (i_ & 7) * 256 + (i_ >> 3);
  const int qb = swz & 31, z = swz >> 5;
  const int b = z >> 4, h = z & 15, g = h >> 2;
  const int q0 = qb * 32;
  const int qi = wq * 16 + (l & 15);       // this lane's q row (local)

  const u16* Qbase = Qg + ((long)b * 1024 + q0) * 2048 + h * 128;
  const u16* Kbase = Kg + (long)b * 1024 * 512 + g * 128;
  const u16* Vbase = Vg + ((long)b * 512 + g * 128) * 1024;  // VT: rows=d, cols=s
  float* attnO = attnF + ((long)z * 1024 + q0) * 1024;

  auto glds16 = [](const u16* gp, u16* lp) {
    __builtin_amdgcn_global_load_lds(
        (const __attribute__((address_space(1))) unsigned int*)gp,
        (__attribute__((address_space(3))) unsigned int*)lp, 16, 0, 0);
  };
  auto stageK = [&](int c, int pb, int sub) {  // [64 s][16 blocks of 8 d]
#pragma unroll
    for (int i = 0; i < 2; ++i) {
      int idx = i * 512 + t;
      int row = idx >> 4, blk = idx & 15;
      glds16(Kbase + (long)(c * 64 + row) * 512 + ((blk ^ (row & 7)) * 8),
             &kv[pb][sub][(i * 512 + w * 64) * 8]);
    }
  };
  auto stageV = [&](int c, int pb, int sub) {  // [128 d][8 blocks of 8 s]
#pragma unroll
    for (int i = 0; i < 2; ++i) {
      int idx = i * 512 + t;
      int row = idx >> 3, blk = idx & 7;
      glds16(Vbase + (long)row * 1024 + c * 64 + ((blk ^ (row & 7)) * 8),
             &kv[pb][sub][(i * 512 + w * 64) * 8]);
    }
  };

  // prologue: Q (1 load/thread, oldest) into p4[0], K0+K1 into kv[0]
  {
    int row = t >> 4, blk = t & 15;
    glds16(Qbase + (long)row * 2048 + ((blk ^ (row & 7)) * 8), &((u16*)p4)[(w * 64) * 8]);
  }
  stageK(0, 0, 0);
  stageK(1, 0, 1);
  asm volatile("s_waitcnt vmcnt(4)" ::: "memory");   // Q retired; K0/K1 in flight
  __builtin_amdgcn_sched_barrier(0);
  __builtin_amdgcn_s_barrier();

  short8 qf[4];
  {
    const u16* pq = (const u16*)p4;
#pragma unroll
    for (int ks = 0; ks < 4; ++ks) {
      int slot = (ks * 4 + (l >> 4)) ^ (qi & 7);
      qf[ks] = *(const short8*)&pq[qi * 128 + slot * 8];
    }
  }

  f32x4 acc[16];
#pragma unroll
  for (int c = 0; c < 16; ++c) acc[c] = (f32x4){0.f, 0.f, 0.f, 0.f};

  // ---- scores: 8 pair-phases; acc[c] = S[k = c*64 + wcol*16 + (l>>4)*4+j][q = qi]
  const int krow = wcol * 16 + (l & 15);
#pragma unroll
  for (int pph = 0; pph < 8; ++pph) {
    if (pph < 7) {
      stageK(2 * pph + 2, (pph + 1) & 1, 0);
      stageK(2 * pph + 3, (pph + 1) & 1, 1);
    } else {
      stageV(0, 0, 0);   // kv[0] free since pair-phase 6
      stageV(1, 0, 1);
    }
    __builtin_amdgcn_s_setprio(1);
#pragma unroll
    for (int sub = 0; sub < 2; ++sub) {
      const int c = 2 * pph + sub;
      const u16* Kl = kv[pph & 1][sub];
#pragma unroll
      for (int ks = 0; ks < 4; ++ks) {
        int slot = (ks * 4 + (l >> 4)) ^ (krow & 7);
        short8 kf = *(const short8*)&Kl[krow * 128 + slot * 8];
        acc[c] = __builtin_amdgcn_mfma_f32_16x16x32_bf16(kf, qf[ks], acc[c], 0, 0, 0);
      }
    }
    __builtin_amdgcn_s_setprio(0);
    __syncthreads();                       // drains stages; next pair ready
  }

  // ---- softmax: per-lane (64 vals) + 2 shfl + cross-wave reduce via red[2]
  const float scale = 0.08838834764831845f;  // 1/sqrt(128)
  float jm[4] = {-1e30f, -1e30f, -1e30f, -1e30f};
#pragma unroll
  for (int c = 0; c < 16; ++c) {
#pragma unroll
    for (int j = 0; j < 4; ++j) jm[j] = fmaxf(jm[j], acc[c][j]);
  }
  float mx = fmaxf(fmaxf(jm[0], jm[1]), fmaxf(jm[2], jm[3]));
  mx = fmaxf(mx, __shfl_xor(mx, 16));
  mx = fmaxf(mx, __shfl_xor(mx, 32));
  if ((l >> 4) == 0) red[0][wcol][qi] = mx;
  __syncthreads();
  const float m = fmaxf(fmaxf(red[0][0][qi], red[0][1][qi]),
                        fmaxf(red[0][2][qi], red[0][3][qi]));
  float s4[4] = {0.f, 0.f, 0.f, 0.f};
#pragma unroll
  for (int c = 0; c < 16; ++c) {
#pragma unroll
    for (int j = 0; j < 4; ++j) {
      float e = __expf((acc[c][j] - m) * scale);
      acc[c][j] = e;
      s4[j] += e;
    }
  }
  float ss = (s4[0] + s4[1]) + (s4[2] + s4[3]);
  ss += __shfl_xor(ss, 16);
  ss += __shfl_xor(ss, 32);
  if ((l >> 4) == 0) red[1][wcol][qi] = ss;
  __syncthreads();
  const float inv = 1.0f / (red[1][0][qi] + red[1][1][qi] +
                            red[1][2][qi] + red[1][3][qi]);

  // ---- normalize in place (acc[] now holds P); attn stores deferred to after PV
#pragma unroll
  for (int c = 0; c < 16; ++c) acc[c] = acc[c] * inv;

  // ---- PV: 8 pair-phases; P pairs through p4 ring, packed at write time
  const int kloc = wcol * 16 + ((l >> 4) * 4);       // k-position within chunk
  auto pwrite = [&](u16* dst, const f32x4& a) {
    int blk = (kloc >> 3) ^ (qi & 7);
    uint2 val;
    val.x = (unsigned)f2bf(a[0]) | ((unsigned)f2bf(a[1]) << 16);
    val.y = (unsigned)f2bf(a[2]) | ((unsigned)f2bf(a[3]) << 16);
    *(uint2*)&dst[qi * 64 + blk * 8 + (kloc & 7)] = val;
  };

  pwrite(p4[0][0], acc[0]);      // P0,P1 -> p4[0] (Q dead)
  pwrite(p4[0][1], acc[1]);
  __syncthreads();               // P0/P1 visible; V0/V1 (staged at pph=7) drained

  f32x4 acc2[2] = {};
  const int prow = wq * 16 + (l & 15);
#pragma unroll
  for (int pp = 0; pp < 8; ++pp) {
    if (pp < 7) {
      pwrite(p4[(pp + 1) & 1][0], acc[2 * pp + 2]);
      pwrite(p4[(pp + 1) & 1][1], acc[2 * pp + 3]);
      stageV(2 * pp + 2, (pp + 1) & 1, 0);
      stageV(2 * pp + 3, (pp + 1) & 1, 1);
    }
    __builtin_amdgcn_s_setprio(1);
#pragma unroll
    for (int sub = 0; sub < 2; ++sub) {
      const u16* Vl = kv[pp & 1][sub];
      const u16* Pl = p4[pp & 1][sub];
#pragma unroll
      for (int ks = 0; ks < 2; ++ks) {
        int ablk = (ks * 4 + (l >> 4)) ^ (prow & 7);
        short8 af = *(const short8*)&Pl[prow * 64 + ablk * 8];
#pragma unroll
        for (int ni = 0; ni < 2; ++ni) {
          int vrow = wcol * 32 + ni * 16 + (l & 15);
          int vslot = (ks * 4 + (l >> 4)) ^ (vrow & 7);
          short8 vf = *(const short8*)&Vl[vrow * 64 + vslot * 8];
          acc2[ni] = __builtin_amdgcn_mfma_f32_16x16x32_bf16(af, vf, acc2[ni], 0, 0, 0);
        }
      }
    }
    __builtin_amdgcn_s_setprio(0);
    __syncthreads();             // drains stages + pwrites; next pair ready
  }

  // ---- deferred attn (f32) stores: non-temporal float4 (never re-read)
#pragma unroll
  for (int c = 0; c < 16; ++c)
    __builtin_nontemporal_store(
        acc[c], (f32x4*)(attnO + (long)qi * 1024 + c * 64 + wcol * 16 + ((l >> 4) * 4)));

  // ---- write AO (bf16): re-read by O-proj -> cached stores
  u16* AObase = AO + ((long)b * 1024 + q0) * 2048 + h * 128;
#pragma unroll
  for (int ni = 0; ni < 2; ++ni)
#pragma unroll
    for (int j = 0; j < 4; ++j) {
      int qq = wq * 16 + (l >> 4) * 4 + j;
      int d = wcol * 32 + ni * 16 + (l & 15);
      AObase[(long)qq * 2048 + d] = f2bf(acc2[ni][j]);
    }
}

// ---------------- host ----------------
extern "C" void kernel_launch(void* const* d_in, const int* in_sizes, int n_in,
                              void* d_out, int out_size, void* d_ws, size_t ws_size,
                              hipStream_t stream) {
  const float* query = (const float*)d_in[0];
  const float* key_  = (const float*)d_in[1];
  const float* value = (const float*)d_in[2];
  const float* Wq = (const float*)d_in[3]; const float* bq = (const float*)d_in[4];
  const float* Wk = (const float*)d_in[5]; const float* bk = (const float*)d_in[6];
  const float* Wv = (const float*)d_in[7]; const float* bv = (const float*)d_in[8];
  const float* Wo = (const float*)d_in[9]; const float* bo = (const float*)d_in[10];

  float* outF  = (float*)d_out;                 // [4,1024,2048]
  float* attnF = outF + 8388608;                // [4,16,1024,1024]

  char* wp = (char*)d_ws;
  u16* WqT = (u16*)wp; wp += 2048L * 2048 * 2;
  u16* WkT = (u16*)wp; wp += 512L * 2048 * 2;
  u16* WvT = (u16*)wp; wp += 512L * 2048 * 2;
  u16* WoT = (u16*)wp; wp += 2048L * 2048 * 2;
  u16* Qb  = (u16*)wp; wp += 4096L * 2048 * 2;
  u16* Kb  = (u16*)wp; wp += 4096L * 512 * 2;
  u16* VT  = (u16*)wp; wp += 4L * 512 * 1024 * 2;
  u16* AO  = (u16*)wp; wp += 4096L * 2048 * 2;

  // merged weight transposes (Wq, Wk, Wv, Wo) — tight 1-D grid, no idle blocks
  TP4 tp;
  tp.s0 = Wq; tp.s1 = Wk; tp.s2 = Wv; tp.s3 = Wo;
  tp.d0 = WqT; tp.d1 = WkT; tp.d2 = WvT; tp.d3 = WoT;
  transpose4_kernel<<<dim3(10240), dim3(32, 8), 0, stream>>>(tp);

  // merged Q/K/V projections: 512 + 128 + 128 = 768 blocks, XCD-swizzled
  Gemm3 g = {};
  g.q[0].A = query; g.q[0].B = WqT; g.q[0].bias = bq; g.q[0].C = Qb;
  g.q[0].N = 2048; g.q[0].K = 2048; g.q[0].lda = 2048; g.q[0].ldb = 2048;
  g.q[0].ldc = 2048; g.q[0].mode = 1; g.q[0].scale = 1.f;
  g.q[1].A = key_; g.q[1].B = WkT; g.q[1].bias = bk; g.q[1].C = Kb;
  g.q[1].N = 512; g.q[1].K = 2048; g.q[1].lda = 2048; g.q[1].ldb = 2048;
  g.q[1].ldc = 512; g.q[1].mode = 1; g.q[1].scale = 1.f;
  g.q[2].A = value; g.q[2].B = WvT; g.q[2].bias = bv; g.q[2].C = VT;
  g.q[2].N = 512; g.q[2].K = 2048; g.q[2].lda = 2048; g.q[2].ldb = 2048;
  g.q[2].ldc = 1024; g.q[2].mode = 2; g.q[2].scale = 1.f;
  g.nb0 = 512; g.nb1 = 128; g.nwg = 768;
  gemm3_kernel<true><<<dim3(768), 256, 0, stream>>>(g);

  // fused scores/softmax/PV: 1-D grid 2048, XCD-swizzled for K/V L2 locality
  fused_attn_kernel<<<dim3(2048), 512, 0, stream>>>(Qb, Kb, VT, attnF, AO);

  // O projection: AO [4096,2048] x WoT + bo -> outF fp32 (XCD-swizzled, nt stores)
  Gemm3 go = {};
  go.q[0].A = AO; go.q[0].B = WoT; go.q[0].bias = bo; go.q[0].C = outF;
  go.q[0].N = 2048; go.q[0].K = 2048; go.q[0].lda = 2048; go.q[0].ldb = 2048;
  go.q[0].ldc = 2048; go.q[0].mode = 0; go.q[0].scale = 1.f;
  go.nb0 = 512; go.nb1 = 0; go.nwg = 512;
  gemm3_kernel<false><<<dim3(512), 256, 0, stream>>>(go);
}

// Round 18
// 252.420 us; speedup vs baseline: 1.1279x; 1.1279x over previous
//
#include <hip/hip_runtime.h>
#include <hip/hip_bf16.h>

typedef unsigned short u16;
typedef __attribute__((ext_vector_type(8))) short short8;
typedef __attribute__((ext_vector_type(4))) float f32x4;

__device__ __forceinline__ u16 f2bf(float f) {
  __hip_bfloat16 h = __float2bfloat16(f);   // HW RNE; compiler packs to v_cvt_pk_bf16_f32
  return *reinterpret_cast<u16*>(&h);
}

// ---------------- merged weight transpose+cvt: dst[c][r] = (bf16)W[r][c] ----------
struct TP4 {
  const float *s0, *s1, *s2, *s3;
  u16 *d0, *d1, *d2, *d3;
};
__global__ __launch_bounds__(256)
void transpose4_kernel(TP4 tp) {
  const int z = blockIdx.z;
  const float* sf; u16* dst; int C;
  if      (z == 0) { sf = tp.s0; dst = tp.d0; C = 2048; }
  else if (z == 1) { sf = tp.s1; dst = tp.d1; C = 512;  }
  else if (z == 2) { sf = tp.s2; dst = tp.d2; C = 512;  }
  else             { sf = tp.s3; dst = tp.d3; C = 2048; }
  const int c0 = blockIdx.x * 32, r0 = blockIdx.y * 32;
  if (c0 >= C) return;
  const int R = 2048;
  __shared__ u16 tile[32][33];
  const int tx = threadIdx.x, ty = threadIdx.y;
#pragma unroll
  for (int i = 0; i < 4; ++i) {
    int r = r0 + ty + i * 8;
    tile[ty + i * 8][tx] = f2bf(sf[(long)r * C + c0 + tx]);
  }
  __syncthreads();
#pragma unroll
  for (int i = 0; i < 4; ++i) {
    int rr = ty + i * 8;
    dst[(long)(c0 + rr) * R + r0 + tx] = tile[tx][rr];
  }
}

// ---------------- GEMM (up to 3 independent problems per dispatch) ----------------
// C[m][n] = scale * sum_k A[m][k] * Bt[n][k] + bias[n]
// mode: 0 = f32 nt-store, 1 = bf16 store, 2 = bf16 transposed-batched VT[b][n][s]
// BK=32 double-buffered: LDS 32 KB/block -> 4+ blocks/CU (was 64 KB / 2 blocks).
#define BM 128
#define BN 128
#define BK 32

struct GemmP {
  const void* A;
  const u16* B;
  const float* bias;
  void* C;
  int N, K, lda, ldb, ldc, mode;
  float scale;
};
struct Gemm3 {
  GemmP q[3];
  int nb0, nb1;   // block counts of problems 0 and 1
  int nwg;        // total blocks (divisible by 8)
};

template<bool AF32>
__global__ __launch_bounds__(256, 4)
void gemm3_kernel(Gemm3 g) {
  __shared__ __align__(16) u16 lds[2][2][BM * BK];   // 32 KB total
  const int t = threadIdx.x;
  const int w = t >> 6, l = t & 63;

  // bijective XCD swizzle (nwg % 8 == 0)
  const int cpx = g.nwg >> 3;
  const int swz = (blockIdx.x & 7) * cpx + (blockIdx.x >> 3);
  int pi, local;
  if (swz < g.nb0)            { pi = 0; local = swz; }
  else if (swz < g.nb0 + g.nb1) { pi = 1; local = swz - g.nb0; }
  else                        { pi = 2; local = swz - g.nb0 - g.nb1; }
  const GemmP p = g.q[pi];

  const int nTn = p.N / BN;
  const int tm = (local / nTn) * BM;
  const int tn = (local % nTn) * BN;

  const u16*   Ab = (const u16*)p.A + (long)tm * p.lda;
  const float* Af = (const float*)p.A + (long)tm * p.lda;
  const u16*   Bt = p.B + (long)tn * p.ldb;

  const int wr = w >> 1, wc = w & 1;
  f32x4 acc[4][4] = {};
  float aR[16];

  // rows are 32 u16 = 4 slots of 8; XOR swizzle slot ^= row&3 (both sides).
  auto stageB = [&](int kt, int buf) {
#pragma unroll
    for (int i = 0; i < 2; ++i) {
      int c = i * 256 + t;
      int row = c >> 2;
      int slot = (c & 3) ^ (row & 3);
      const u16* gp = Bt + kt * BK + (long)row * p.ldb + slot * 8;
      u16* lp = &lds[buf][1][(i * 256 + w * 64) * 8];
      __builtin_amdgcn_global_load_lds(
          (const __attribute__((address_space(1))) unsigned int*)gp,
          (__attribute__((address_space(3))) unsigned int*)lp, 16, 0, 0);
    }
  };
  auto stageA_bf16 = [&](int kt, int buf) {
#pragma unroll
    for (int i = 0; i < 2; ++i) {
      int c = i * 256 + t;
      int row = c >> 2;
      int slot = (c & 3) ^ (row & 3);
      const u16* gp = Ab + kt * BK + (long)row * p.lda + slot * 8;
      u16* lp = &lds[buf][0][(i * 256 + w * 64) * 8];
      __builtin_amdgcn_global_load_lds(
          (const __attribute__((address_space(1))) unsigned int*)gp,
          (__attribute__((address_space(3))) unsigned int*)lp, 16, 0, 0);
    }
  };
  auto loadA_f32 = [&](int kt) {
    const float* g0 = Af + kt * BK;
#pragma unroll
    for (int i = 0; i < 2; ++i) {
      int c = i * 256 + t;
      int row = c >> 2, slot = c & 3;
      const float4* gp = (const float4*)(g0 + (long)row * p.lda + slot * 8);
      float4 v0 = gp[0], v1 = gp[1];
      aR[i * 8 + 0] = v0.x; aR[i * 8 + 1] = v0.y; aR[i * 8 + 2] = v0.z; aR[i * 8 + 3] = v0.w;
      aR[i * 8 + 4] = v1.x; aR[i * 8 + 5] = v1.y; aR[i * 8 + 6] = v1.z; aR[i * 8 + 7] = v1.w;
    }
  };
  auto writeA = [&](int buf) {
#pragma unroll
    for (int i = 0; i < 2; ++i) {
      int c = i * 256 + t;
      int row = c >> 2, slot = c & 3;
      short8 o;
#pragma unroll
      for (int j = 0; j < 8; ++j) o[j] = (short)f2bf(aR[i * 8 + j]);
      *(short8*)&lds[buf][0][row * 32 + ((slot ^ (row & 3)) * 8)] = o;
    }
  };
  auto compute = [&](int buf) {
    const u16* At  = lds[buf][0];
    const u16* Btl = lds[buf][1];
    short8 af[4], bfr[4];
#pragma unroll
    for (int mi = 0; mi < 4; ++mi) {
      int row = wr * 64 + mi * 16 + (l & 15);
      int slot = (l >> 4) ^ (row & 3);
      af[mi] = *(const short8*)&At[row * 32 + slot * 8];
    }
#pragma unroll
    for (int ni = 0; ni < 4; ++ni) {
      int row = wc * 64 + ni * 16 + (l & 15);
      int slot = (l >> 4) ^ (row & 3);
      bfr[ni] = *(const short8*)&Btl[row * 32 + slot * 8];
    }
#pragma unroll
    for (int mi = 0; mi < 4; ++mi)
#pragma unroll
      for (int ni = 0; ni < 4; ++ni)
        acc[mi][ni] = __builtin_amdgcn_mfma_f32_16x16x32_bf16(
            af[mi], bfr[ni], acc[mi][ni], 0, 0, 0);
  };

  const int nkt = p.K / BK;
  if (AF32) { loadA_f32(0); stageB(0, 0); writeA(0); }
  else      { stageA_bf16(0, 0); stageB(0, 0); }
  __syncthreads();

  int buf = 0;
  for (int kt = 0; kt < nkt; ++kt) {
    if (kt + 1 < nkt) {
      if (AF32) loadA_f32(kt + 1); else stageA_bf16(kt + 1, buf ^ 1);
      stageB(kt + 1, buf ^ 1);
    }
    compute(buf);
    if (AF32 && kt + 1 < nkt) writeA(buf ^ 1);
    __syncthreads();
    buf ^= 1;
  }

  const int cl = l & 15, rj = (l >> 4) * 4;
#pragma unroll
  for (int mi = 0; mi < 4; ++mi) {
#pragma unroll
    for (int ni = 0; ni < 4; ++ni) {
      int cidx = tn + wc * 64 + ni * 16 + cl;
      float bv = p.bias ? p.bias[cidx] : 0.f;
#pragma unroll
      for (int j = 0; j < 4; ++j) {
        int r = tm + wr * 64 + mi * 16 + rj + j;
        float v = acc[mi][ni][j] * p.scale + bv;
        if (p.mode == 2) {
          // VT[b][cidx][s]: b = r>>10, s = r&1023
          ((u16*)p.C)[((long)(r >> 10)) * 524288 + (long)cidx * 1024 + (r & 1023)] = f2bf(v);
        } else {
          long idx = (long)r * p.ldc + cidx;
          if (p.mode == 1) ((u16*)p.C)[idx] = f2bf(v);
          else             __builtin_nontemporal_store(v, &((float*)p.C)[idx]);
        }
      }
    }
  }
}

// ---------------- fused scores -> softmax -> PV (swapped-MFMA, paired phases) -----
// 1-D grid 2048, XCD-swizzled. 512 threads = 8 waves (wq 0..1, wcol 0..3).
// Scores: 8 pair-phases (kv[2][2] ring). PV: 8 pair-phases (same ring) with P
// pairs through p4[2][2]. red (512B) aliases p4[1]. attn f32 stores after PV,
// NON-TEMPORAL (never re-read; keeps L2 for K/V).
__global__ __launch_bounds__(512, 4)
void fused_attn_kernel(const u16* __restrict__ Qg, const u16* __restrict__ Kg,
                       const u16* __restrict__ Vg, float* __restrict__ attnF,
                       u16* __restrict__ AO) {
  __shared__ __align__(16) u16 kv[2][2][64 * 128];  // 64 KB (pair ring)
  __shared__ __align__(16) u16 p4[2][2][32 * 64];   // 16 KB: Q stage / P pair ring
  float* red = (float*)&p4[1][0][0];                // [4][32] floats, aliases p4[1]

  const int t = threadIdx.x;
  const int w = t >> 6, l = t & 63;
  const int wq = w >> 2, wcol = w & 3;
  const int i_ = blockIdx.x;
  const int swz = (i_ & 7) * 256 + (i_ >> 3);
  const int qb = swz & 31, z = swz >> 5;
  const int b = z >> 4, h = z & 15, g = h >> 2;
  const int q0 = qb * 32;
  const int qi = wq * 16 + (l & 15);       // this lane's q row (local)

  const u16* Qbase = Qg + ((long)b * 1024 + q0) * 2048 + h * 128;
  const u16* Kbase = Kg + (long)b * 1024 * 512 + g * 128;
  const u16* Vbase = Vg + ((long)b * 512 + g * 128) * 1024;  // VT: rows=d, cols=s
  float* attnO = attnF + ((long)z * 1024 + q0) * 1024;

  auto glds16 = [](const u16* gp, u16* lp) {
    __builtin_amdgcn_global_load_lds(
        (const __attribute__((address_space(1))) unsigned int*)gp,
        (__attribute__((address_space(3))) unsigned int*)lp, 16, 0, 0);
  };
  auto stageK = [&](int c, int pb, int sub) {  // [64 s][16 blocks of 8 d]
#pragma unroll
    for (int i = 0; i < 2; ++i) {
      int idx = i * 512 + t;
      int row = idx >> 4, blk = idx & 15;
      glds16(Kbase + (long)(c * 64 + row) * 512 + ((blk ^ (row & 7)) * 8),
             &kv[pb][sub][(i * 512 + w * 64) * 8]);
    }
  };
  auto stageV = [&](int c, int pb, int sub) {  // [128 d][8 blocks of 8 s]
#pragma unroll
    for (int i = 0; i < 2; ++i) {
      int idx = i * 512 + t;
      int row = idx >> 3, blk = idx & 7;
      glds16(Vbase + (long)row * 1024 + c * 64 + ((blk ^ (row & 7)) * 8),
             &kv[pb][sub][(i * 512 + w * 64) * 8]);
    }
  };

  // prologue: Q (1 load/thread) into p4[0] (8 KB), K0+K1 into kv[0]
  {
    int row = t >> 4, blk = t & 15;
    glds16(Qbase + (long)row * 2048 + ((blk ^ (row & 7)) * 8), &((u16*)p4)[(w * 64) * 8]);
  }
  stageK(0, 0, 0);
  stageK(1, 0, 1);
  __syncthreads();

  short8 qf[4];
  {
    const u16* pq = (const u16*)p4;
#pragma unroll
    for (int ks = 0; ks < 4; ++ks) {
      int slot = (ks * 4 + (l >> 4)) ^ (qi & 7);
      qf[ks] = *(const short8*)&pq[qi * 128 + slot * 8];
    }
  }

  f32x4 acc[16];
#pragma unroll
  for (int c = 0; c < 16; ++c) acc[c] = (f32x4){0.f, 0.f, 0.f, 0.f};

  // ---- scores: 8 pair-phases; acc[c] = S[k = c*64 + wcol*16 + (l>>4)*4+j][q = qi]
  const int krow = wcol * 16 + (l & 15);
#pragma unroll
  for (int pph = 0; pph < 8; ++pph) {
    if (pph < 7) {
      stageK(2 * pph + 2, (pph + 1) & 1, 0);
      stageK(2 * pph + 3, (pph + 1) & 1, 1);
    } else {
      stageV(0, 0, 0);   // kv[0] free since pair-phase 6
      stageV(1, 0, 1);
    }
    __builtin_amdgcn_s_setprio(1);
#pragma unroll
    for (int sub = 0; sub < 2; ++sub) {
      const int c = 2 * pph + sub;
      const u16* Kl = kv[pph & 1][sub];
#pragma unroll
      for (int ks = 0; ks < 4; ++ks) {
        int slot = (ks * 4 + (l >> 4)) ^ (krow & 7);
        short8 kf = *(const short8*)&Kl[krow * 128 + slot * 8];
        acc[c] = __builtin_amdgcn_mfma_f32_16x16x32_bf16(kf, qf[ks], acc[c], 0, 0, 0);
      }
    }
    __builtin_amdgcn_s_setprio(0);
    __syncthreads();                       // drains stages; next pair ready
  }

  // ---- softmax: per-lane (64 vals) + 2 shfl + cross-wave reduce via red (1 buffer)
  const float scale = 0.08838834764831845f;  // 1/sqrt(128)
  float jm[4] = {-1e30f, -1e30f, -1e30f, -1e30f};
#pragma unroll
  for (int c = 0; c < 16; ++c) {
#pragma unroll
    for (int j = 0; j < 4; ++j) jm[j] = fmaxf(jm[j], acc[c][j]);
  }
  float mx = fmaxf(fmaxf(jm[0], jm[1]), fmaxf(jm[2], jm[3]));
  mx = fmaxf(mx, __shfl_xor(mx, 16));
  mx = fmaxf(mx, __shfl_xor(mx, 32));
  if ((l >> 4) == 0) red[wcol * 32 + qi] = mx;
  __syncthreads();
  const float m = fmaxf(fmaxf(red[0 * 32 + qi], red[1 * 32 + qi]),
                        fmaxf(red[2 * 32 + qi], red[3 * 32 + qi]));
  __syncthreads();   // protect red reuse (single buffer)
  float s4[4] = {0.f, 0.f, 0.f, 0.f};
#pragma unroll
  for (int c = 0; c < 16; ++c) {
#pragma unroll
    for (int j = 0; j < 4; ++j) {
      float e = __expf((acc[c][j] - m) * scale);
      acc[c][j] = e;
      s4[j] += e;
    }
  }
  float ss = (s4[0] + s4[1]) + (s4[2] + s4[3]);
  ss += __shfl_xor(ss, 16);
  ss += __shfl_xor(ss, 32);
  if ((l >> 4) == 0) red[wcol * 32 + qi] = ss;
  __syncthreads();
  const float inv = 1.0f / (red[0 * 32 + qi] + red[1 * 32 + qi] +
                            red[2 * 32 + qi] + red[3 * 32 + qi]);

  // ---- normalize in place (acc[] now holds P); attn stores deferred to after PV
#pragma unroll
  for (int c = 0; c < 16; ++c) acc[c] = acc[c] * inv;

  // ---- PV: 8 pair-phases; P pairs through p4 ring, packed at write time
  const int kloc = wcol * 16 + ((l >> 4) * 4);       // k-position within chunk
  auto pwrite = [&](u16* dst, const f32x4& a) {
    int blk = (kloc >> 3) ^ (qi & 7);
    uint2 val;
    val.x = (unsigned)f2bf(a[0]) | ((unsigned)f2bf(a[1]) << 16);
    val.y = (unsigned)f2bf(a[2]) | ((unsigned)f2bf(a[3]) << 16);
    *(uint2*)&dst[qi * 64 + blk * 8 + (kloc & 7)] = val;
  };

  pwrite(p4[0][0], acc[0]);      // P0,P1 -> p4[0] (Q dead; red still intact in p4[1])
  pwrite(p4[0][1], acc[1]);
  __syncthreads();               // P0/P1 visible; V0/V1 (staged at pph=7) drained

  f32x4 acc2[2] = {};
  const int prow = wq * 16 + (l & 15);
#pragma unroll
  for (int pp = 0; pp < 8; ++pp) {
    if (pp < 7) {
      pwrite(p4[(pp + 1) & 1][0], acc[2 * pp + 2]);  // red dead from here on
      pwrite(p4[(pp + 1) & 1][1], acc[2 * pp + 3]);
      stageV(2 * pp + 2, (pp + 1) & 1, 0);
      stageV(2 * pp + 3, (pp + 1) & 1, 1);
    }
    __builtin_amdgcn_s_setprio(1);
#pragma unroll
    for (int sub = 0; sub < 2; ++sub) {
      const u16* Vl = kv[pp & 1][sub];
      const u16* Pl = p4[pp & 1][sub];
#pragma unroll
      for (int ks = 0; ks < 2; ++ks) {
        int ablk = (ks * 4 + (l >> 4)) ^ (prow & 7);
        short8 af = *(const short8*)&Pl[prow * 64 + ablk * 8];
#pragma unroll
        for (int ni = 0; ni < 2; ++ni) {
          int vrow = wcol * 32 + ni * 16 + (l & 15);
          int vslot = (ks * 4 + (l >> 4)) ^ (vrow & 7);
          short8 vf = *(const short8*)&Vl[vrow * 64 + vslot * 8];
          acc2[ni] = __builtin_amdgcn_mfma_f32_16x16x32_bf16(af, vf, acc2[ni], 0, 0, 0);
        }
      }
    }
    __builtin_amdgcn_s_setprio(0);
    __syncthreads();             // drains stages + pwrites; next pair ready
  }

  // ---- deferred attn (f32) stores: non-temporal float4 (never re-read)
#pragma unroll
  for (int c = 0; c < 16; ++c)
    __builtin_nontemporal_store(
        acc[c], (f32x4*)(attnO + (long)qi * 1024 + c * 64 + wcol * 16 + ((l >> 4) * 4)));

  // ---- write AO (bf16): re-read by O-proj -> cached stores
  u16* AObase = AO + ((long)b * 1024 + q0) * 2048 + h * 128;
#pragma unroll
  for (int ni = 0; ni < 2; ++ni)
#pragma unroll
    for (int j = 0; j < 4; ++j) {
      int qq = wq * 16 + (l >> 4) * 4 + j;
      int d = wcol * 32 + ni * 16 + (l & 15);
      AObase[(long)qq * 2048 + d] = f2bf(acc2[ni][j]);
    }
}

// ---------------- host ----------------
extern "C" void kernel_launch(void* const* d_in, const int* in_sizes, int n_in,
                              void* d_out, int out_size, void* d_ws, size_t ws_size,
                              hipStream_t stream) {
  const float* query = (const float*)d_in[0];
  const float* key_  = (const float*)d_in[1];
  const float* value = (const float*)d_in[2];
  const float* Wq = (const float*)d_in[3]; const float* bq = (const float*)d_in[4];
  const float* Wk = (const float*)d_in[5]; const float* bk = (const float*)d_in[6];
  const float* Wv = (const float*)d_in[7]; const float* bv = (const float*)d_in[8];
  const float* Wo = (const float*)d_in[9]; const float* bo = (const float*)d_in[10];

  float* outF  = (float*)d_out;                 // [4,1024,2048]
  float* attnF = outF + 8388608;                // [4,16,1024,1024]

  char* wp = (char*)d_ws;
  u16* WqT = (u16*)wp; wp += 2048L * 2048 * 2;
  u16* WkT = (u16*)wp; wp += 512L * 2048 * 2;
  u16* WvT = (u16*)wp; wp += 512L * 2048 * 2;
  u16* WoT = (u16*)wp; wp += 2048L * 2048 * 2;
  u16* Qb  = (u16*)wp; wp += 4096L * 2048 * 2;
  u16* Kb  = (u16*)wp; wp += 4096L * 512 * 2;
  u16* VT  = (u16*)wp; wp += 4L * 512 * 1024 * 2;
  u16* AO  = (u16*)wp; wp += 4096L * 2048 * 2;

  // merged weight transposes (Wq, Wk, Wv, Wo)
  TP4 tp;
  tp.s0 = Wq; tp.s1 = Wk; tp.s2 = Wv; tp.s3 = Wo;
  tp.d0 = WqT; tp.d1 = WkT; tp.d2 = WvT; tp.d3 = WoT;
  transpose4_kernel<<<dim3(64, 64, 4), dim3(32, 8), 0, stream>>>(tp);

  // merged Q/K/V projections: 512 + 128 + 128 = 768 blocks, XCD-swizzled
  Gemm3 g = {};
  g.q[0].A = query; g.q[0].B = WqT; g.q[0].bias = bq; g.q[0].C = Qb;
  g.q[0].N = 2048; g.q[0].K = 2048; g.q[0].lda = 2048; g.q[0].ldb = 2048;
  g.q[0].ldc = 2048; g.q[0].mode = 1; g.q[0].scale = 1.f;
  g.q[1].A = key_; g.q[1].B = WkT; g.q[1].bias = bk; g.q[1].C = Kb;
  g.q[1].N = 512; g.q[1].K = 2048; g.q[1].lda = 2048; g.q[1].ldb = 2048;
  g.q[1].ldc = 512; g.q[1].mode = 1; g.q[1].scale = 1.f;
  g.q[2].A = value; g.q[2].B = WvT; g.q[2].bias = bv; g.q[2].C = VT;
  g.q[2].N = 512; g.q[2].K = 2048; g.q[2].lda = 2048; g.q[2].ldb = 2048;
  g.q[2].ldc = 1024; g.q[2].mode = 2; g.q[2].scale = 1.f;
  g.nb0 = 512; g.nb1 = 128; g.nwg = 768;
  gemm3_kernel<true><<<dim3(768), 256, 0, stream>>>(g);

  // fused scores/softmax/PV: 1-D grid 2048, XCD-swizzled for K/V L2 locality
  fused_attn_kernel<<<dim3(2048), 512, 0, stream>>>(Qb, Kb, VT, attnF, AO);

  // O projection: AO [4096,2048] x WoT + bo -> outF fp32 (XCD-swizzled, nt stores)
  Gemm3 go = {};
  go.q[0].A = AO; go.q[0].B = WoT; go.q[0].bias = bo; go.q[0].C = outF;
  go.q[0].N = 2048; go.q[0].K = 2048; go.q[0].lda = 2048; go.q[0].ldb = 2048;
  go.q[0].ldc = 2048; go.q[0].mode = 0; go.q[0].scale = 1.f;
  go.nb0 = 512; go.nb1 = 0; go.nwg = 512;
  gemm3_kernel<false><<<dim3(512), 256, 0, stream>>>(go);
}